// Round 4
// baseline (464.898 us; speedup 1.0000x reference)
//
#include <hip/hip_runtime.h>

typedef __bf16 bf16;
typedef bf16 bf16x8 __attribute__((ext_vector_type(8)));
typedef bf16 bf16x4 __attribute__((ext_vector_type(4)));
typedef float f32x4 __attribute__((ext_vector_type(4)));

#define MFMA(a, b, c) __builtin_amdgcn_mfma_f32_16x16x32_bf16((a), (b), (c), 0, 0, 0)

// Problem constants
// N=32, BSZ=512, NE=7, DIN=512, DH=256 ; M = N*BSZ*NE = 114688 rows
// out: marginal [32,512,7] = 114688 floats, joint [32,512,128] = 2097152 floats

// ---------------------------------------------------------------------------
// small: merged k_bsum (blocks 0..511) + k_prep (blocks 512..609).
// Saves one kernel-launch gap; both are tiny.
// ---------------------------------------------------------------------------
__global__ __launch_bounds__(256) void k_small(const float* __restrict__ ctx,
                                               const float* __restrict__ R0,
                                               const float* __restrict__ r0,
                                               const float* __restrict__ R1,
                                               const float* __restrict__ r1,
                                               float* __restrict__ bsum,
                                               const float* __restrict__ W0,
                                               const float* __restrict__ W1,
                                               const float* __restrict__ W2,
                                               bf16* __restrict__ W0f,
                                               bf16* __restrict__ W1f,
                                               bf16* __restrict__ W2f) {
  const int t = threadIdx.x;
  if (blockIdx.x >= 512) {
    // ---- prep: pack W0^T, W1^T, W2^T into MFMA A-fragment order (bf16).
    // A-frag (16x16x32): lane l holds A[m=tile*16+(l&15)][k=ks*32+(l>>4)*8+j]
    int g = (blockIdx.x - 512) * 256 + t;          // 0..25087
    if (g < 16384) {                       // W0^T: 16 mtiles x 16 ksteps x 64 lanes
      int mt = g >> 10, ks = (g >> 6) & 15, lane = g & 63;
      int m = mt * 16 + (lane & 15);
      int kb = ks * 32 + (lane >> 4) * 8;
      bf16x8 v;
#pragma unroll
      for (int j = 0; j < 8; ++j) v[j] = (bf16)W0[(kb + j) * 256 + m];
      *(bf16x8*)&W0f[g * 8] = v;
    } else if (g < 24576) {                // W1^T: 16 mtiles x 8 ksteps x 64 lanes
      int h = g - 16384;
      int mt = h >> 9, ks = (h >> 6) & 7, lane = h & 63;
      int m = mt * 16 + (lane & 15);
      int kb = ks * 32 + (lane >> 4) * 8;
      bf16x8 v;
#pragma unroll
      for (int j = 0; j < 8; ++j) v[j] = (bf16)W1[(kb + j) * 256 + m];
      *(bf16x8*)&W1f[h * 8] = v;
    } else {                               // W2^T: 1 mtile (rows 0,1 valid) x 8 ksteps
      int h = g - 24576;
      int ks = h >> 6, lane = h & 63;
      int c = lane & 15;
      int kb = ks * 32 + (lane >> 4) * 8;
      bf16x8 v;
#pragma unroll
      for (int j = 0; j < 8; ++j) v[j] = (c < 2) ? (bf16)W2[(kb + j) * 2 + c] : (bf16)0.0f;
      *(bf16x8*)&W2f[h * 8] = v;
    }
    return;
  }
  // ---- bsum: relation MLP + pairwise pre-sum over the 21 pairs
  __shared__ float ctx_l[105], R0_l[320], r0_l[64], R1_l[192], r1_l[3];
  __shared__ float h2[21 * 65];        // +1 pad col to dodge bank conflicts
  __shared__ float bp[63];
  const int b = blockIdx.x;
  if (t < 105) ctx_l[t] = ctx[b * 105 + t];
  for (int i = t; i < 320; i += 256) R0_l[i] = R0[i];
  if (t < 64) r0_l[t] = r0[t];
  if (t < 192) R1_l[t] = R1[t];
  if (t < 3) r1_l[t] = r1[t];
  __syncthreads();
  for (int idx = t; idx < 1344; idx += 256) {
    int p = idx >> 6, u = idx & 63;
    float a = r0_l[u];
#pragma unroll
    for (int x = 0; x < 5; ++x) a += ctx_l[p * 5 + x] * R0_l[x * 64 + u];
    h2[p * 65 + u] = fmaxf(a, 0.f);
  }
  __syncthreads();
  if (t < 63) {
    int p = t / 3, y = t - p * 3;
    float a = r1_l[y];
    for (int u = 0; u < 64; ++u) a += h2[p * 65 + u] * R1_l[u * 3 + y];
    bp[t] = a;
  }
  __syncthreads();
  if (t < 128) {
    // state s = t; entity i bit = (s >> (6-i)) & 1 (entity 0 most significant)
    float a = 0.f;
    int pi = 0;
#pragma unroll
    for (int i = 0; i < 7; ++i)
#pragma unroll
      for (int j = i + 1; j < 7; ++j) {
        int bi = (t >> (6 - i)) & 1, bj = (t >> (6 - j)) & 1;
        a += bp[pi * 3 + bi + bj];
        ++pi;
      }
    bsum[b * 128 + t] = a;
  }
}

// ---------------------------------------------------------------------------
// unary MLP, fully fused, transposed GEMMs:
//   D0 = W0^T(256x512) * X^T(512x64)  -> h0[m][n] in LDS (n contiguous)
//   D1 = W1^T(256x256) * h0^T         -> h1[m][n] in LDS
//   D2 = W2^T(2x256)   * h1^T         -> un[m][2] to global
// Block: 256 threads (4 waves), 64 example-rows. Wave w owns D-rows [64w,64w+64).
// Layer 0 is BARRIER-FREE: the B-fragment is loaded DIRECTLY from global
// (lane l needs 8 consecutive f32 of example-row nt*16+l16 at col it*32+lq*8;
// a wave touches 16 rows x 128 B contiguous). No inp_lds, no STAGE repack,
// no ds round-trip. Cross-wave 4x re-read of input is absorbed by L1/L2;
// HBM first-touch traffic is unchanged. LDS = 35 KB -> 3 blocks/CU real.
// ---------------------------------------------------------------------------
__global__ __launch_bounds__(256, 3) void k_unary(const float* __restrict__ input,
                                                  const bf16* __restrict__ W0f,
                                                  const bf16* __restrict__ W1f,
                                                  const bf16* __restrict__ W2f,
                                                  const float* __restrict__ b0,
                                                  const float* __restrict__ b1,
                                                  const float* __restrict__ b2,
                                                  float* __restrict__ un) {
  __shared__ bf16 h_lds[64 * 264];       // 64 rows x 256 (+8 pad) bf16 = 33 KB
  __shared__ float part_lds[512];        // layer-2 cross-wave partials

  const int tid = threadIdx.x;
  const int wave = tid >> 6;
  const int lane = tid & 63;
  const int l16 = lane & 15;
  const int lq = lane >> 4;            // 0..3
  const long m0 = (long)blockIdx.x * 64;

  f32x4 acc[4][4];
#pragma unroll
  for (int i = 0; i < 4; ++i)
#pragma unroll
    for (int j = 0; j < 4; ++j) acc[i][j] = (f32x4){0.f, 0.f, 0.f, 0.f};

  // ---- layer 0: K=512, 16 ksteps, zero barriers, direct-global B-frags ---
  const float* bbase = input + (m0 + l16) * 512 + lq * 8;
#pragma unroll 2
  for (int it = 0; it < 16; ++it) {
    bf16x8 bfr[4];
#pragma unroll
    for (int nt = 0; nt < 4; ++nt) {
      const float* p = bbase + nt * (16 * 512) + it * 32;
      float4 lo = *(const float4*)p;
      float4 hi = *(const float4*)(p + 4);
      bf16x8 v;
      v[0] = (bf16)lo.x; v[1] = (bf16)lo.y; v[2] = (bf16)lo.z; v[3] = (bf16)lo.w;
      v[4] = (bf16)hi.x; v[5] = (bf16)hi.y; v[6] = (bf16)hi.z; v[7] = (bf16)hi.w;
      bfr[nt] = v;
    }
#pragma unroll
    for (int mt = 0; mt < 4; ++mt) {
      bf16x8 a = *(const bf16x8*)&W0f[(((wave * 4 + mt) * 16 + it) * 64 + lane) * 8];
#pragma unroll
      for (int nt = 0; nt < 4; ++nt) acc[mt][nt] = MFMA(a, bfr[nt], acc[mt][nt]);
    }
  }

  // epilogue 0: h0 = relu(D0 + b0) -> h_lds[m][n]
#pragma unroll
  for (int mt = 0; mt < 4; ++mt) {
    const int nbase = (wave * 4 + mt) * 16 + lq * 4;
    const float4 bb = *(const float4*)&b0[nbase];
#pragma unroll
    for (int nt = 0; nt < 4; ++nt) {
      const int m = nt * 16 + l16;
      bf16x4 hv;
      hv[0] = (bf16)fmaxf(acc[mt][nt][0] + bb.x, 0.f);
      hv[1] = (bf16)fmaxf(acc[mt][nt][1] + bb.y, 0.f);
      hv[2] = (bf16)fmaxf(acc[mt][nt][2] + bb.z, 0.f);
      hv[3] = (bf16)fmaxf(acc[mt][nt][3] + bb.w, 0.f);
      *(bf16x4*)&h_lds[m * 264 + nbase] = hv;
    }
  }
  __syncthreads();

  // ---- layer 1: K=256, 8 ksteps ----------------------------------------
#pragma unroll
  for (int i = 0; i < 4; ++i)
#pragma unroll
    for (int j = 0; j < 4; ++j) acc[i][j] = (f32x4){0.f, 0.f, 0.f, 0.f};
  for (int ks = 0; ks < 8; ++ks) {
    bf16x8 bfr[4];
#pragma unroll
    for (int nt = 0; nt < 4; ++nt)
      bfr[nt] = *(const bf16x8*)&h_lds[(nt * 16 + l16) * 264 + ks * 32 + lq * 8];
#pragma unroll
    for (int mt = 0; mt < 4; ++mt) {
      bf16x8 a = *(const bf16x8*)&W1f[(((wave * 4 + mt) * 8 + ks) * 64 + lane) * 8];
#pragma unroll
      for (int nt = 0; nt < 4; ++nt) acc[mt][nt] = MFMA(a, bfr[nt], acc[mt][nt]);
    }
  }
  __syncthreads();   // everyone done reading h0 before overwrite

  // epilogue 1: h1 = relu(D1 + b1) -> h_lds[m][n]
#pragma unroll
  for (int mt = 0; mt < 4; ++mt) {
    const int nbase = (wave * 4 + mt) * 16 + lq * 4;
    const float4 bb = *(const float4*)&b1[nbase];
#pragma unroll
    for (int nt = 0; nt < 4; ++nt) {
      const int m = nt * 16 + l16;
      bf16x4 hv;
      hv[0] = (bf16)fmaxf(acc[mt][nt][0] + bb.x, 0.f);
      hv[1] = (bf16)fmaxf(acc[mt][nt][1] + bb.y, 0.f);
      hv[2] = (bf16)fmaxf(acc[mt][nt][2] + bb.z, 0.f);
      hv[3] = (bf16)fmaxf(acc[mt][nt][3] + bb.w, 0.f);
      *(bf16x4*)&h_lds[m * 264 + nbase] = hv;
    }
  }
  __syncthreads();

  // ---- layer 2: K=256 split across waves (2 ksteps each) ----------------
  f32x4 acc2[4];
#pragma unroll
  for (int i = 0; i < 4; ++i) acc2[i] = (f32x4){0.f, 0.f, 0.f, 0.f};
#pragma unroll
  for (int s = 0; s < 2; ++s) {
    const int ks = wave * 2 + s;
    bf16x8 a = *(const bf16x8*)&W2f[(ks * 64 + lane) * 8];
#pragma unroll
    for (int nt = 0; nt < 4; ++nt) {
      bf16x8 b = *(const bf16x8*)&h_lds[(nt * 16 + l16) * 264 + ks * 32 + lq * 8];
      acc2[nt] = MFMA(a, b, acc2[nt]);
    }
  }
  // valid rows c=0,1 live in regs 0,1 of lanes with lq==0
  if (lane < 16) {
#pragma unroll
    for (int nt = 0; nt < 4; ++nt) {
      part_lds[((wave * 4 + nt) * 16 + lane) * 2 + 0] = acc2[nt][0];
      part_lds[((wave * 4 + nt) * 16 + lane) * 2 + 1] = acc2[nt][1];
    }
  }
  __syncthreads();
  if (tid < 128) {
    const int mloc = tid >> 1, c = tid & 1;
    const int nt = mloc >> 4, l = mloc & 15;
    float s = b2[c];
#pragma unroll
    for (int w2 = 0; w2 < 4; ++w2) s += part_lds[((w2 * 4 + nt) * 16 + l) * 2 + c];
    un[(m0 + mloc) * 2 + c] = s;
  }
}

// ---------------------------------------------------------------------------
// joint + marginals: ONE WAVE per (n,b) row. Lane l holds states l (bit6=0)
// and l+64 (bit6=1) -> entity-0 axis reduces in-register; 6-bit butterfly
// subtrees on c = e_lo + e_hi give all per-bit sums; one extra tree on e_hi
// gives the entity-0 one-sum. Zero barriers, zero LDS. un row loaded via
// wave-uniform (readfirstlane) pointer -> scalar loads, free broadcast.
// ---------------------------------------------------------------------------
__global__ __launch_bounds__(256) void k_joint(const float* __restrict__ un,
                                               const float* __restrict__ bsum,
                                               float* __restrict__ out_marg,
                                               float* __restrict__ out_joint) {
  const int lane = threadIdx.x & 63;
  const int w = threadIdx.x >> 6;
  const int wrow = __builtin_amdgcn_readfirstlane(blockIdx.x * 4 + w);  // n*512+b
  const int b = wrow & 511;

  const float* up = un + (long)wrow * 14;   // uniform -> s_load
  float u[14];
#pragma unroll
  for (int k = 0; k < 14; ++k) u[k] = up[k];

  const float* bp = bsum + b * 128;
  const float bs_lo = bp[lane];
  const float bs_hi = bp[64 + lane];

  float umid = 0.f;
#pragma unroll
  for (int i = 1; i < 7; ++i) umid += u[2 * i + ((lane >> (6 - i)) & 1)];
  const float j_lo = bs_lo + umid + u[0];
  const float j_hi = bs_hi + umid + u[1];

  float mm = fmaxf(j_lo, j_hi);
#pragma unroll
  for (int o = 32; o; o >>= 1) mm = fmaxf(mm, __shfl_xor(mm, o, 64));
  const float e_lo = __expf(j_lo - mm);
  const float e_hi = __expf(j_hi - mm);
  const float c = e_lo + e_hi;

  // shared butterfly subtrees on c (lane bits 0..5; entity i <-> bit 6-i)
  float a1 = c + __shfl_xor(c, 16, 64);
  float A  = a1 + __shfl_xor(a1, 32, 64);       // reduced over bits {4,5}
  float e1 = c + __shfl_xor(c, 4, 64);
  float E23 = e1 + __shfl_xor(e1, 8, 64);       // reduced over bits {2,3}
  float r1_ = A + __shfl_xor(A, 4, 64);
  float R2345 = r1_ + __shfl_xor(r1_, 8, 64);   // bits {2,3,4,5}
  float s1_ = A + __shfl_xor(A, 1, 64);
  float R0145 = s1_ + __shfl_xor(s1_, 2, 64);   // bits {0,1,4,5}
  float u1_ = E23 + __shfl_xor(E23, 1, 64);
  float R0123 = u1_ + __shfl_xor(u1_, 2, 64);   // bits {0,1,2,3}

  float v0 = R2345 + __shfl_xor(R2345, 2, 64);  // varies only with bit0
  float v1 = R2345 + __shfl_xor(R2345, 1, 64);  // bit1
  float v2 = R0145 + __shfl_xor(R0145, 8, 64);  // bit2
  float v3 = R0145 + __shfl_xor(R0145, 4, 64);  // bit3
  float v4 = R0123 + __shfl_xor(R0123, 32, 64); // bit4
  float v5 = R0123 + __shfl_xor(R0123, 16, 64); // bit5
  const float T = v0 + __shfl_xor(v0, 1, 64);

  // entity-0 one-sum: full tree on e_hi
  float th = e_hi;
#pragma unroll
  for (int o = 32; o; o >>= 1) th += __shfl_xor(th, o, 64);

  const float lT = __logf(T);
  float* oj = out_joint + (long)wrow * 128;
  oj[lane] = (j_lo - mm) - lT;
  oj[64 + lane] = (j_hi - mm) - lT;

  // broadcast per-bit one-sums to all lanes (v_k at lane 1<<k is the bit-k=1 sum)
  const float S0 = __shfl(v0, 1, 64);
  const float S1 = __shfl(v1, 2, 64);
  const float S2 = __shfl(v2, 4, 64);
  const float S3 = __shfl(v3, 8, 64);
  const float S4 = __shfl(v4, 16, 64);
  const float S5 = __shfl(v5, 32, 64);
  if (lane < 7) {
    // entity 0 -> th; entity i (1..6) -> lane bit 6-i
    const float s1v = (lane == 0) ? th
                    : (lane == 1) ? S5
                    : (lane == 2) ? S4
                    : (lane == 3) ? S3
                    : (lane == 4) ? S2
                    : (lane == 5) ? S1 : S0;
    const float s0v = T - s1v;
    out_marg[(long)wrow * 7 + lane] = __logf(s1v) - __logf(s0v);
  }
}

// ---------------------------------------------------------------------------
extern "C" void kernel_launch(void* const* d_in, const int* in_sizes, int n_in,
                              void* d_out, int out_size, void* d_ws, size_t ws_size,
                              hipStream_t stream) {
  const float* input = (const float*)d_in[0];
  const float* ctx   = (const float*)d_in[1];
  // d_in[2]=lang_input, d_in[3]=num_markables: unused by the reference
  const float* W0 = (const float*)d_in[4];
  const float* b0 = (const float*)d_in[5];
  const float* W1 = (const float*)d_in[6];
  const float* b1 = (const float*)d_in[7];
  const float* W2 = (const float*)d_in[8];
  const float* b2 = (const float*)d_in[9];
  const float* R0 = (const float*)d_in[10];
  const float* r0 = (const float*)d_in[11];
  const float* R1 = (const float*)d_in[12];
  const float* r1 = (const float*)d_in[13];

  char* ws = (char*)d_ws;
  bf16* W0f  = (bf16*)(ws + 0);         // 262144 B
  bf16* W1f  = (bf16*)(ws + 262144);    // 131072 B
  bf16* W2f  = (bf16*)(ws + 393216);    //   8192 B
  float* un  = (float*)(ws + 401408);   // 917504 B
  float* bsm = (float*)(ws + 1318912);  // 262144 B

  float* out_marg = (float*)d_out;
  float* out_joint = out_marg + 114688;

  hipLaunchKernelGGL(k_small, dim3(610), dim3(256), 0, stream,
                     ctx, R0, r0, R1, r1, bsm, W0, W1, W2, W0f, W1f, W2f);
  hipLaunchKernelGGL(k_unary, dim3(1792), dim3(256), 0, stream,
                     input, W0f, W1f, W2f, b0, b1, b2, un);
  hipLaunchKernelGGL(k_joint, dim3(4096), dim3(256), 0, stream, un, bsm, out_marg, out_joint);
}

// Round 5
// 389.176 us; speedup vs baseline: 1.1946x; 1.1946x over previous
//
#include <hip/hip_runtime.h>

typedef __bf16 bf16;
typedef bf16 bf16x8 __attribute__((ext_vector_type(8)));
typedef bf16 bf16x4 __attribute__((ext_vector_type(4)));
typedef float f32x4 __attribute__((ext_vector_type(4)));

#define MFMA(a, b, c) __builtin_amdgcn_mfma_f32_16x16x32_bf16((a), (b), (c), 0, 0, 0)

// Problem constants
// N=32, BSZ=512, NE=7, DIN=512, DH=256 ; M = N*BSZ*NE = 114688 rows
// out: marginal [32,512,7] = 114688 floats, joint [32,512,128] = 2097152 floats

// ---------------------------------------------------------------------------
// small: merged k_bsum (blocks 0..511) + k_prep (blocks 512..609).
// ---------------------------------------------------------------------------
__global__ __launch_bounds__(256) void k_small(const float* __restrict__ ctx,
                                               const float* __restrict__ R0,
                                               const float* __restrict__ r0,
                                               const float* __restrict__ R1,
                                               const float* __restrict__ r1,
                                               float* __restrict__ bsum,
                                               const float* __restrict__ W0,
                                               const float* __restrict__ W1,
                                               const float* __restrict__ W2,
                                               bf16* __restrict__ W0f,
                                               bf16* __restrict__ W1f,
                                               bf16* __restrict__ W2f) {
  const int t = threadIdx.x;
  if (blockIdx.x >= 512) {
    // ---- prep: pack W0^T, W1^T, W2^T into MFMA A-fragment order (bf16).
    // A-frag (16x16x32): lane l holds A[m=tile*16+(l&15)][k=ks*32+(l>>4)*8+j]
    int g = (blockIdx.x - 512) * 256 + t;          // 0..25087
    if (g < 16384) {                       // W0^T: 16 mtiles x 16 ksteps x 64 lanes
      int mt = g >> 10, ks = (g >> 6) & 15, lane = g & 63;
      int m = mt * 16 + (lane & 15);
      int kb = ks * 32 + (lane >> 4) * 8;
      bf16x8 v;
#pragma unroll
      for (int j = 0; j < 8; ++j) v[j] = (bf16)W0[(kb + j) * 256 + m];
      *(bf16x8*)&W0f[g * 8] = v;
    } else if (g < 24576) {                // W1^T: 16 mtiles x 8 ksteps x 64 lanes
      int h = g - 16384;
      int mt = h >> 9, ks = (h >> 6) & 7, lane = h & 63;
      int m = mt * 16 + (lane & 15);
      int kb = ks * 32 + (lane >> 4) * 8;
      bf16x8 v;
#pragma unroll
      for (int j = 0; j < 8; ++j) v[j] = (bf16)W1[(kb + j) * 256 + m];
      *(bf16x8*)&W1f[h * 8] = v;
    } else {                               // W2^T: 1 mtile (rows 0,1 valid) x 8 ksteps
      int h = g - 24576;
      int ks = h >> 6, lane = h & 63;
      int c = lane & 15;
      int kb = ks * 32 + (lane >> 4) * 8;
      bf16x8 v;
#pragma unroll
      for (int j = 0; j < 8; ++j) v[j] = (c < 2) ? (bf16)W2[(kb + j) * 2 + c] : (bf16)0.0f;
      *(bf16x8*)&W2f[h * 8] = v;
    }
    return;
  }
  // ---- bsum: relation MLP + pairwise pre-sum over the 21 pairs
  __shared__ float ctx_l[105], R0_l[320], r0_l[64], R1_l[192], r1_l[3];
  __shared__ float h2[21 * 65];
  __shared__ float bp[63];
  const int b = blockIdx.x;
  if (t < 105) ctx_l[t] = ctx[b * 105 + t];
  for (int i = t; i < 320; i += 256) R0_l[i] = R0[i];
  if (t < 64) r0_l[t] = r0[t];
  if (t < 192) R1_l[t] = R1[t];
  if (t < 3) r1_l[t] = r1[t];
  __syncthreads();
  for (int idx = t; idx < 1344; idx += 256) {
    int p = idx >> 6, u = idx & 63;
    float a = r0_l[u];
#pragma unroll
    for (int x = 0; x < 5; ++x) a += ctx_l[p * 5 + x] * R0_l[x * 64 + u];
    h2[p * 65 + u] = fmaxf(a, 0.f);
  }
  __syncthreads();
  if (t < 63) {
    int p = t / 3, y = t - p * 3;
    float a = r1_l[y];
    for (int u = 0; u < 64; ++u) a += h2[p * 65 + u] * R1_l[u * 3 + y];
    bp[t] = a;
  }
  __syncthreads();
  if (t < 128) {
    float a = 0.f;
    int pi = 0;
#pragma unroll
    for (int i = 0; i < 7; ++i)
#pragma unroll
      for (int j = i + 1; j < 7; ++j) {
        int bi = (t >> (6 - i)) & 1, bj = (t >> (6 - j)) & 1;
        a += bp[pi * 3 + bi + bj];
        ++pi;
      }
    bsum[b * 128 + t] = a;
  }
}

// ---------------------------------------------------------------------------
// unary MLP, fully fused, transposed GEMMs.
// Layer 0: input staged f32 via ASYNC global_load_lds (16B/lane), BK=32,
// double-buffered, ONE barrier per K-step. LDS slab rows are linear (g_load_lds
// writes base+lane*16); chunk permutation is applied on the GLOBAL source and
// identically on the LDS read (XOR involution chunk^(row&7)) -> conflict-free.
// h0/h1 live in a TILE-BLOCKED LDS layout: tile (nt, ks) = 16 examples x 32 k
// = 1024 B contiguous; lane reads exactly one distinct 16-B chunk per frag
// (ds_read_b128 at the 8-cycle minimum, no conflicts). Within-tile chunk is
// XOR-swizzled (q ^ (n&3)) so epilogue writes also spread across banks.
// ---------------------------------------------------------------------------
__global__ __launch_bounds__(256, 3) void k_unary(const float* __restrict__ input,
                                                  const bf16* __restrict__ W0f,
                                                  const bf16* __restrict__ W1f,
                                                  const bf16* __restrict__ W2f,
                                                  const float* __restrict__ b0,
                                                  const float* __restrict__ b1,
                                                  const float* __restrict__ b2,
                                                  float* __restrict__ un) {
  __shared__ __align__(16) float inp_lds[2][64 * 32];  // 2 x (64 rows x 32 f32) = 16 KB
  __shared__ __align__(16) bf16 h_lds[32 * 512];       // 32 tiles x 512 bf16 = 32 KB
  __shared__ float part_lds[512];                      // layer-2 partials (2 KB)

  const int tid = threadIdx.x;
  const int wave = tid >> 6;
  const int lane = tid & 63;
  const int l16 = lane & 15;
  const int lq = lane >> 4;            // 0..3
  const long m0 = (long)blockIdx.x * 64;

  f32x4 acc[4][4];
#pragma unroll
  for (int i = 0; i < 4; ++i)
#pragma unroll
    for (int j = 0; j < 4; ++j) acc[i][j] = (f32x4){0.f, 0.f, 0.f, 0.f};

  // async stage of one BK=32 slab: wave w covers rows w*16..w*16+15, 2 instrs
  // lane l: row = w*16 + i*8 + (l>>3); LDS dst linear chunk l&7; global source
  // chunk = (l&7) ^ (l>>3)  (== (l&7) ^ (row&7); read side applies same XOR)
#define GSTAGE(BUF, IT)                                                         \
  do {                                                                          \
    _Pragma("unroll")                                                           \
    for (int i_ = 0; i_ < 2; ++i_) {                                            \
      const float* g_ = input + (m0 + wave * 16 + i_ * 8 + (lane >> 3)) * 512 + \
                        (IT) * 32 + (((lane & 7) ^ (lane >> 3)) * 4);           \
      __builtin_amdgcn_global_load_lds(                                         \
          (const __attribute__((address_space(1))) unsigned int*)g_,            \
          (__attribute__((address_space(3))) unsigned int*)                     \
              &inp_lds[BUF][(wave * 16 + i_ * 8) * 32],                         \
          16, 0, 0);                                                            \
    }                                                                           \
  } while (0)

  GSTAGE(0, 0);

  // ---- layer 0: K=512, 16 ksteps of BK=32, double-buffered ---------------
  for (int it = 0; it < 16; ++it) {
    const int cur = it & 1;
    __syncthreads();                       // drains slab 'cur'; syncs buffer reuse
    if (it < 15) GSTAGE(cur ^ 1, it + 1);  // async next slab (in flight over MFMA)
    bf16x8 bfr[4];
    const int e = l16 & 7;
#pragma unroll
    for (int nt = 0; nt < 4; ++nt) {
      const float* bp_ = &inp_lds[cur][(nt * 16 + l16) * 32];
      f32x4 lo = *(const f32x4*)&bp_[((2 * lq) ^ e) * 4];
      f32x4 hi = *(const f32x4*)&bp_[((2 * lq + 1) ^ e) * 4];
      bf16x8 v;
      v[0] = (bf16)lo[0]; v[1] = (bf16)lo[1]; v[2] = (bf16)lo[2]; v[3] = (bf16)lo[3];
      v[4] = (bf16)hi[0]; v[5] = (bf16)hi[1]; v[6] = (bf16)hi[2]; v[7] = (bf16)hi[3];
      bfr[nt] = v;
    }
#pragma unroll
    for (int mt = 0; mt < 4; ++mt) {
      bf16x8 a = *(const bf16x8*)&W0f[(((wave * 4 + mt) * 16 + it) * 64 + lane) * 8];
#pragma unroll
      for (int nt = 0; nt < 4; ++nt) acc[mt][nt] = MFMA(a, bfr[nt], acc[mt][nt]);
    }
  }

  // epilogue 0: h0 = relu(D0 + b0) -> tile-blocked h_lds
  // acc[mt][nt][g]: DH row = (wave*4+mt)*16 + lq*4 + g ; example = nt*16+l16
#pragma unroll
  for (int mt = 0; mt < 4; ++mt) {
    const int W = wave * 4 + mt;
    const int nbase = W * 16 + lq * 4;
    const float4 bb = *(const float4*)&b0[nbase];
    const int ks2 = W >> 1;
    const int q = (W & 1) * 2 + (lq >> 1);   // 16-B chunk index of kk within tile
    const int h8 = (lq & 1) * 4;             // bf16 offset within chunk
#pragma unroll
    for (int nt = 0; nt < 4; ++nt) {
      bf16x4 hv;
      hv[0] = (bf16)fmaxf(acc[mt][nt][0] + bb.x, 0.f);
      hv[1] = (bf16)fmaxf(acc[mt][nt][1] + bb.y, 0.f);
      hv[2] = (bf16)fmaxf(acc[mt][nt][2] + bb.z, 0.f);
      hv[3] = (bf16)fmaxf(acc[mt][nt][3] + bb.w, 0.f);
      *(bf16x4*)&h_lds[(nt * 8 + ks2) * 512 + l16 * 32 + ((q ^ (l16 & 3)) * 8) + h8] = hv;
    }
  }
  __syncthreads();

  // ---- layer 1: K=256, 8 ksteps; B-frag = one b128 per lane, conflict-free
#pragma unroll
  for (int i = 0; i < 4; ++i)
#pragma unroll
    for (int j = 0; j < 4; ++j) acc[i][j] = (f32x4){0.f, 0.f, 0.f, 0.f};
  for (int ks = 0; ks < 8; ++ks) {
    bf16x8 bfr[4];
#pragma unroll
    for (int nt = 0; nt < 4; ++nt)
      bfr[nt] = *(const bf16x8*)&h_lds[(nt * 8 + ks) * 512 + l16 * 32 +
                                       ((lq ^ (l16 & 3)) * 8)];
#pragma unroll
    for (int mt = 0; mt < 4; ++mt) {
      bf16x8 a = *(const bf16x8*)&W1f[(((wave * 4 + mt) * 8 + ks) * 64 + lane) * 8];
#pragma unroll
      for (int nt = 0; nt < 4; ++nt) acc[mt][nt] = MFMA(a, bfr[nt], acc[mt][nt]);
    }
  }
  __syncthreads();   // everyone done reading h0 before overwrite

  // epilogue 1: h1 = relu(D1 + b1) -> same tile-blocked layout
#pragma unroll
  for (int mt = 0; mt < 4; ++mt) {
    const int W = wave * 4 + mt;
    const int nbase = W * 16 + lq * 4;
    const float4 bb = *(const float4*)&b1[nbase];
    const int ks2 = W >> 1;
    const int q = (W & 1) * 2 + (lq >> 1);
    const int h8 = (lq & 1) * 4;
#pragma unroll
    for (int nt = 0; nt < 4; ++nt) {
      bf16x4 hv;
      hv[0] = (bf16)fmaxf(acc[mt][nt][0] + bb.x, 0.f);
      hv[1] = (bf16)fmaxf(acc[mt][nt][1] + bb.y, 0.f);
      hv[2] = (bf16)fmaxf(acc[mt][nt][2] + bb.z, 0.f);
      hv[3] = (bf16)fmaxf(acc[mt][nt][3] + bb.w, 0.f);
      *(bf16x4*)&h_lds[(nt * 8 + ks2) * 512 + l16 * 32 + ((q ^ (l16 & 3)) * 8) + h8] = hv;
    }
  }
  __syncthreads();

  // ---- layer 2: K=256 split across waves (2 ksteps each) ----------------
  f32x4 acc2[4];
#pragma unroll
  for (int i = 0; i < 4; ++i) acc2[i] = (f32x4){0.f, 0.f, 0.f, 0.f};
#pragma unroll
  for (int s = 0; s < 2; ++s) {
    const int ks = wave * 2 + s;
    bf16x8 a = *(const bf16x8*)&W2f[(ks * 64 + lane) * 8];
#pragma unroll
    for (int nt = 0; nt < 4; ++nt) {
      bf16x8 b = *(const bf16x8*)&h_lds[(nt * 8 + ks) * 512 + l16 * 32 +
                                        ((lq ^ (l16 & 3)) * 8)];
      acc2[nt] = MFMA(a, b, acc2[nt]);
    }
  }
  // valid rows c=0,1 live in regs 0,1 of lanes with lq==0
  if (lane < 16) {
#pragma unroll
    for (int nt = 0; nt < 4; ++nt) {
      part_lds[((wave * 4 + nt) * 16 + lane) * 2 + 0] = acc2[nt][0];
      part_lds[((wave * 4 + nt) * 16 + lane) * 2 + 1] = acc2[nt][1];
    }
  }
  __syncthreads();
  if (tid < 128) {
    const int mloc = tid >> 1, c = tid & 1;
    const int nt = mloc >> 4, l = mloc & 15;
    float s = b2[c];
#pragma unroll
    for (int w2 = 0; w2 < 4; ++w2) s += part_lds[((w2 * 4 + nt) * 16 + l) * 2 + c];
    un[(m0 + mloc) * 2 + c] = s;
  }
#undef GSTAGE
}

// ---------------------------------------------------------------------------
// joint + marginals: ONE WAVE per (n,b) row. Lane l holds states l (bit6=0)
// and l+64 (bit6=1); butterfly subtrees on c = e_lo+e_hi give per-bit sums.
// Zero barriers, zero LDS.
// ---------------------------------------------------------------------------
__global__ __launch_bounds__(256) void k_joint(const float* __restrict__ un,
                                               const float* __restrict__ bsum,
                                               float* __restrict__ out_marg,
                                               float* __restrict__ out_joint) {
  const int lane = threadIdx.x & 63;
  const int w = threadIdx.x >> 6;
  const int wrow = __builtin_amdgcn_readfirstlane(blockIdx.x * 4 + w);  // n*512+b
  const int b = wrow & 511;

  const float* up = un + (long)wrow * 14;   // uniform -> s_load
  float u[14];
#pragma unroll
  for (int k = 0; k < 14; ++k) u[k] = up[k];

  const float* bp = bsum + b * 128;
  const float bs_lo = bp[lane];
  const float bs_hi = bp[64 + lane];

  float umid = 0.f;
#pragma unroll
  for (int i = 1; i < 7; ++i) umid += u[2 * i + ((lane >> (6 - i)) & 1)];
  const float j_lo = bs_lo + umid + u[0];
  const float j_hi = bs_hi + umid + u[1];

  float mm = fmaxf(j_lo, j_hi);
#pragma unroll
  for (int o = 32; o; o >>= 1) mm = fmaxf(mm, __shfl_xor(mm, o, 64));
  const float e_lo = __expf(j_lo - mm);
  const float e_hi = __expf(j_hi - mm);
  const float c = e_lo + e_hi;

  // shared butterfly subtrees on c (lane bits 0..5; entity i <-> bit 6-i)
  float a1 = c + __shfl_xor(c, 16, 64);
  float A  = a1 + __shfl_xor(a1, 32, 64);       // reduced over bits {4,5}
  float e1 = c + __shfl_xor(c, 4, 64);
  float E23 = e1 + __shfl_xor(e1, 8, 64);       // reduced over bits {2,3}
  float r1_ = A + __shfl_xor(A, 4, 64);
  float R2345 = r1_ + __shfl_xor(r1_, 8, 64);   // bits {2,3,4,5}
  float s1_ = A + __shfl_xor(A, 1, 64);
  float R0145 = s1_ + __shfl_xor(s1_, 2, 64);   // bits {0,1,4,5}
  float u1_ = E23 + __shfl_xor(E23, 1, 64);
  float R0123 = u1_ + __shfl_xor(u1_, 2, 64);   // bits {0,1,2,3}

  float v0 = R2345 + __shfl_xor(R2345, 2, 64);  // varies only with bit0
  float v1 = R2345 + __shfl_xor(R2345, 1, 64);  // bit1
  float v2 = R0145 + __shfl_xor(R0145, 8, 64);  // bit2
  float v3 = R0145 + __shfl_xor(R0145, 4, 64);  // bit3
  float v4 = R0123 + __shfl_xor(R0123, 32, 64); // bit4
  float v5 = R0123 + __shfl_xor(R0123, 16, 64); // bit5
  const float T = v0 + __shfl_xor(v0, 1, 64);

  // entity-0 one-sum: full tree on e_hi
  float th = e_hi;
#pragma unroll
  for (int o = 32; o; o >>= 1) th += __shfl_xor(th, o, 64);

  const float lT = __logf(T);
  float* oj = out_joint + (long)wrow * 128;
  oj[lane] = (j_lo - mm) - lT;
  oj[64 + lane] = (j_hi - mm) - lT;

  // broadcast per-bit one-sums (v_k at lane 1<<k is the bit-k=1 sum)
  const float S0 = __shfl(v0, 1, 64);
  const float S1 = __shfl(v1, 2, 64);
  const float S2 = __shfl(v2, 4, 64);
  const float S3 = __shfl(v3, 8, 64);
  const float S4 = __shfl(v4, 16, 64);
  const float S5 = __shfl(v5, 32, 64);
  if (lane < 7) {
    const float s1v = (lane == 0) ? th
                    : (lane == 1) ? S5
                    : (lane == 2) ? S4
                    : (lane == 3) ? S3
                    : (lane == 4) ? S2
                    : (lane == 5) ? S1 : S0;
    const float s0v = T - s1v;
    out_marg[(long)wrow * 7 + lane] = __logf(s1v) - __logf(s0v);
  }
}

// ---------------------------------------------------------------------------
extern "C" void kernel_launch(void* const* d_in, const int* in_sizes, int n_in,
                              void* d_out, int out_size, void* d_ws, size_t ws_size,
                              hipStream_t stream) {
  const float* input = (const float*)d_in[0];
  const float* ctx   = (const float*)d_in[1];
  // d_in[2]=lang_input, d_in[3]=num_markables: unused by the reference
  const float* W0 = (const float*)d_in[4];
  const float* b0 = (const float*)d_in[5];
  const float* W1 = (const float*)d_in[6];
  const float* b1 = (const float*)d_in[7];
  const float* W2 = (const float*)d_in[8];
  const float* b2 = (const float*)d_in[9];
  const float* R0 = (const float*)d_in[10];
  const float* r0 = (const float*)d_in[11];
  const float* R1 = (const float*)d_in[12];
  const float* r1 = (const float*)d_in[13];

  char* ws = (char*)d_ws;
  bf16* W0f  = (bf16*)(ws + 0);         // 262144 B
  bf16* W1f  = (bf16*)(ws + 262144);    // 131072 B
  bf16* W2f  = (bf16*)(ws + 393216);    //   8192 B
  float* un  = (float*)(ws + 401408);   // 917504 B
  float* bsm = (float*)(ws + 1318912);  // 262144 B

  float* out_marg = (float*)d_out;
  float* out_joint = out_marg + 114688;

  hipLaunchKernelGGL(k_small, dim3(610), dim3(256), 0, stream,
                     ctx, R0, r0, R1, r1, bsm, W0, W1, W2, W0f, W1f, W2f);
  hipLaunchKernelGGL(k_unary, dim3(1792), dim3(256), 0, stream,
                     input, W0f, W1f, W2f, b0, b1, b2, un);
  hipLaunchKernelGGL(k_joint, dim3(4096), dim3(256), 0, stream, un, bsm, out_marg, out_joint);
}

// Round 6
// 388.864 us; speedup vs baseline: 1.1955x; 1.0008x over previous
//
#include <hip/hip_runtime.h>

typedef __bf16 bf16;
typedef bf16 bf16x8 __attribute__((ext_vector_type(8)));
typedef bf16 bf16x4 __attribute__((ext_vector_type(4)));
typedef float f32x4 __attribute__((ext_vector_type(4)));

#define MFMA(a, b, c) __builtin_amdgcn_mfma_f32_16x16x32_bf16((a), (b), (c), 0, 0, 0)

// Problem constants
// N=32, BSZ=512, NE=7, DIN=512, DH=256 ; M = N*BSZ*NE = 114688 rows
// out: marginal [32,512,7] = 114688 floats, joint [32,512,128] = 2097152 floats

// ---------------------------------------------------------------------------
// small: merged k_bsum (blocks 0..511) + k_prep (blocks 512..609).
// ---------------------------------------------------------------------------
__global__ __launch_bounds__(256) void k_small(const float* __restrict__ ctx,
                                               const float* __restrict__ R0,
                                               const float* __restrict__ r0,
                                               const float* __restrict__ R1,
                                               const float* __restrict__ r1,
                                               float* __restrict__ bsum,
                                               const float* __restrict__ W0,
                                               const float* __restrict__ W1,
                                               const float* __restrict__ W2,
                                               bf16* __restrict__ W0f,
                                               bf16* __restrict__ W1f,
                                               bf16* __restrict__ W2f) {
  const int t = threadIdx.x;
  if (blockIdx.x >= 512) {
    // ---- prep: pack W0^T, W1^T, W2^T into MFMA A-fragment order (bf16).
    // A-frag (16x16x32): lane l holds A[m=tile*16+(l&15)][k=ks*32+(l>>4)*8+j]
    int g = (blockIdx.x - 512) * 256 + t;          // 0..25087
    if (g < 16384) {                       // W0^T: 16 mtiles x 16 ksteps x 64 lanes
      int mt = g >> 10, ks = (g >> 6) & 15, lane = g & 63;
      int m = mt * 16 + (lane & 15);
      int kb = ks * 32 + (lane >> 4) * 8;
      bf16x8 v;
#pragma unroll
      for (int j = 0; j < 8; ++j) v[j] = (bf16)W0[(kb + j) * 256 + m];
      *(bf16x8*)&W0f[g * 8] = v;
    } else if (g < 24576) {                // W1^T: 16 mtiles x 8 ksteps x 64 lanes
      int h = g - 16384;
      int mt = h >> 9, ks = (h >> 6) & 7, lane = h & 63;
      int m = mt * 16 + (lane & 15);
      int kb = ks * 32 + (lane >> 4) * 8;
      bf16x8 v;
#pragma unroll
      for (int j = 0; j < 8; ++j) v[j] = (bf16)W1[(kb + j) * 256 + m];
      *(bf16x8*)&W1f[h * 8] = v;
    } else {                               // W2^T: 1 mtile (rows 0,1 valid) x 8 ksteps
      int h = g - 24576;
      int ks = h >> 6, lane = h & 63;
      int c = lane & 15;
      int kb = ks * 32 + (lane >> 4) * 8;
      bf16x8 v;
#pragma unroll
      for (int j = 0; j < 8; ++j) v[j] = (c < 2) ? (bf16)W2[(kb + j) * 2 + c] : (bf16)0.0f;
      *(bf16x8*)&W2f[h * 8] = v;
    }
    return;
  }
  // ---- bsum: relation MLP + pairwise pre-sum over the 21 pairs
  __shared__ float ctx_l[105], R0_l[320], r0_l[64], R1_l[192], r1_l[3];
  __shared__ float h2[21 * 65];
  __shared__ float bp[63];
  const int b = blockIdx.x;
  if (t < 105) ctx_l[t] = ctx[b * 105 + t];
  for (int i = t; i < 320; i += 256) R0_l[i] = R0[i];
  if (t < 64) r0_l[t] = r0[t];
  if (t < 192) R1_l[t] = R1[t];
  if (t < 3) r1_l[t] = r1[t];
  __syncthreads();
  for (int idx = t; idx < 1344; idx += 256) {
    int p = idx >> 6, u = idx & 63;
    float a = r0_l[u];
#pragma unroll
    for (int x = 0; x < 5; ++x) a += ctx_l[p * 5 + x] * R0_l[x * 64 + u];
    h2[p * 65 + u] = fmaxf(a, 0.f);
  }
  __syncthreads();
  if (t < 63) {
    int p = t / 3, y = t - p * 3;
    float a = r1_l[y];
    for (int u = 0; u < 64; ++u) a += h2[p * 65 + u] * R1_l[u * 3 + y];
    bp[t] = a;
  }
  __syncthreads();
  if (t < 128) {
    float a = 0.f;
    int pi = 0;
#pragma unroll
    for (int i = 0; i < 7; ++i)
#pragma unroll
      for (int j = i + 1; j < 7; ++j) {
        int bi = (t >> (6 - i)) & 1, bj = (t >> (6 - j)) & 1;
        a += bp[pi * 3 + bi + bj];
        ++pi;
      }
    bsum[b * 128 + t] = a;
  }
}

// ---------------------------------------------------------------------------
// unary MLP, fully fused, transposed GEMMs:
//   D0 = W0^T(256x512) * X^T(512x64)  -> h0[m][n] in LDS (n contiguous)
//   D1 = W1^T(256x256) * h0^T         -> h1[m][n] in LDS
//   D2 = W2^T(2x256)   * h1^T         -> un[m][2] to global
// Block: 256 threads (4 waves), 64 example-rows. Wave w owns D-rows [64w,64w+64).
// Layer 0: BK=128, reg-staged bf16-on-write, double-buffered -> FOUR barriers
// total for layer 0 (vs 8 at BK=64, 16 at BK=32). 64 MFMAs per barrier phase.
// LDS 70.6 KB -> 2 blocks/CU; __launch_bounds__(256,2) keeps VGPR cap at 256
// so the 8xfloat4 prefetch + acc[4][4] cannot spill.
// ---------------------------------------------------------------------------
__global__ __launch_bounds__(256, 2) void k_unary(const float* __restrict__ input,
                                                  const bf16* __restrict__ W0f,
                                                  const bf16* __restrict__ W1f,
                                                  const bf16* __restrict__ W2f,
                                                  const float* __restrict__ b0,
                                                  const float* __restrict__ b1,
                                                  const float* __restrict__ b2,
                                                  float* __restrict__ un) {
  __shared__ bf16 inp_lds[2][64 * 136];  // 2 x 64 rows x 128 (+8 pad) bf16 = 34.8 KB
  __shared__ bf16 h_lds[64 * 264];       // 64 rows x 256 (+8 pad) bf16 = 33.8 KB
  __shared__ float part_lds[512];        // layer-2 partials (2 KB)

  const int tid = threadIdx.x;
  const int wave = tid >> 6;
  const int lane = tid & 63;
  const int l16 = lane & 15;
  const int lq = lane >> 4;            // 0..3
  const long m0 = (long)blockIdx.x * 64;

  f32x4 acc[4][4];
#pragma unroll
  for (int i = 0; i < 4; ++i)
#pragma unroll
    for (int j = 0; j < 4; ++j) acc[i][j] = (f32x4){0.f, 0.f, 0.f, 0.f};

  // staging map: thread -> (row r, 32-float chunk q) of the BK=128 slab
  const int r = tid >> 2;              // 0..63
  const int q = tid & 3;               // 0..3
  const float* gp = input + (m0 + r) * 512 + q * 32;
  float4 x[8];
#pragma unroll
  for (int j = 0; j < 8; ++j) x[j] = ((const float4*)gp)[j];

#define STAGE(BUF)                                                              \
  do {                                                                          \
    _Pragma("unroll")                                                           \
    for (int c_ = 0; c_ < 4; ++c_) {                                            \
      bf16x8 wv;                                                                \
      wv[0] = (bf16)x[2 * c_].x;     wv[1] = (bf16)x[2 * c_].y;                 \
      wv[2] = (bf16)x[2 * c_].z;     wv[3] = (bf16)x[2 * c_].w;                 \
      wv[4] = (bf16)x[2 * c_ + 1].x; wv[5] = (bf16)x[2 * c_ + 1].y;             \
      wv[6] = (bf16)x[2 * c_ + 1].z; wv[7] = (bf16)x[2 * c_ + 1].w;             \
      *(bf16x8*)&inp_lds[BUF][r * 136 + q * 32 + c_ * 8] = wv;                  \
    }                                                                           \
  } while (0)

  STAGE(0);
  __syncthreads();

  // ---- layer 0: K=512, 4 iters of BK=128, double-buffered ----------------
  for (int it = 0; it < 4; ++it) {
    const int cur = it & 1;
    // prefetch next slab from HBM (lands under the 64-MFMA phase)
    if (it < 3) {
      gp += 128;
#pragma unroll
      for (int j = 0; j < 8; ++j) x[j] = ((const float4*)gp)[j];
    }
#pragma unroll
    for (int kk = 0; kk < 4; ++kk) {
      bf16x8 bfr[4];
#pragma unroll
      for (int nt = 0; nt < 4; ++nt)
        bfr[nt] = *(const bf16x8*)&inp_lds[cur][(nt * 16 + l16) * 136 + kk * 32 + lq * 8];
#pragma unroll
      for (int mt = 0; mt < 4; ++mt) {
        bf16x8 a =
            *(const bf16x8*)&W0f[(((wave * 4 + mt) * 16 + it * 4 + kk) * 64 + lane) * 8];
#pragma unroll
        for (int nt = 0; nt < 4; ++nt) acc[mt][nt] = MFMA(a, bfr[nt], acc[mt][nt]);
      }
    }
    // stage next slab into the other buffer (its readers finished before the
    // barrier that opened this iteration)
    if (it < 3) STAGE(cur ^ 1);
    __syncthreads();
  }
#undef STAGE

  // epilogue 0: h0 = relu(D0 + b0) -> h_lds[m][n]
#pragma unroll
  for (int mt = 0; mt < 4; ++mt) {
    const int nbase = (wave * 4 + mt) * 16 + lq * 4;
    const float4 bb = *(const float4*)&b0[nbase];
#pragma unroll
    for (int nt = 0; nt < 4; ++nt) {
      const int m = nt * 16 + l16;
      bf16x4 hv;
      hv[0] = (bf16)fmaxf(acc[mt][nt][0] + bb.x, 0.f);
      hv[1] = (bf16)fmaxf(acc[mt][nt][1] + bb.y, 0.f);
      hv[2] = (bf16)fmaxf(acc[mt][nt][2] + bb.z, 0.f);
      hv[3] = (bf16)fmaxf(acc[mt][nt][3] + bb.w, 0.f);
      *(bf16x4*)&h_lds[m * 264 + nbase] = hv;
    }
  }
  __syncthreads();

  // ---- layer 1: K=256, 8 ksteps ----------------------------------------
#pragma unroll
  for (int i = 0; i < 4; ++i)
#pragma unroll
    for (int j = 0; j < 4; ++j) acc[i][j] = (f32x4){0.f, 0.f, 0.f, 0.f};
  for (int ks = 0; ks < 8; ++ks) {
    bf16x8 bfr[4];
#pragma unroll
    for (int nt = 0; nt < 4; ++nt)
      bfr[nt] = *(const bf16x8*)&h_lds[(nt * 16 + l16) * 264 + ks * 32 + lq * 8];
#pragma unroll
    for (int mt = 0; mt < 4; ++mt) {
      bf16x8 a = *(const bf16x8*)&W1f[(((wave * 4 + mt) * 8 + ks) * 64 + lane) * 8];
#pragma unroll
      for (int nt = 0; nt < 4; ++nt) acc[mt][nt] = MFMA(a, bfr[nt], acc[mt][nt]);
    }
  }
  __syncthreads();   // everyone done reading h0 before overwrite

  // epilogue 1: h1 = relu(D1 + b1) -> h_lds[m][n]
#pragma unroll
  for (int mt = 0; mt < 4; ++mt) {
    const int nbase = (wave * 4 + mt) * 16 + lq * 4;
    const float4 bb = *(const float4*)&b1[nbase];
#pragma unroll
    for (int nt = 0; nt < 4; ++nt) {
      const int m = nt * 16 + l16;
      bf16x4 hv;
      hv[0] = (bf16)fmaxf(acc[mt][nt][0] + bb.x, 0.f);
      hv[1] = (bf16)fmaxf(acc[mt][nt][1] + bb.y, 0.f);
      hv[2] = (bf16)fmaxf(acc[mt][nt][2] + bb.z, 0.f);
      hv[3] = (bf16)fmaxf(acc[mt][nt][3] + bb.w, 0.f);
      *(bf16x4*)&h_lds[m * 264 + nbase] = hv;
    }
  }
  __syncthreads();

  // ---- layer 2: K=256 split across waves (2 ksteps each) ----------------
  f32x4 acc2[4];
#pragma unroll
  for (int i = 0; i < 4; ++i) acc2[i] = (f32x4){0.f, 0.f, 0.f, 0.f};
#pragma unroll
  for (int s = 0; s < 2; ++s) {
    const int ks = wave * 2 + s;
    bf16x8 a = *(const bf16x8*)&W2f[(ks * 64 + lane) * 8];
#pragma unroll
    for (int nt = 0; nt < 4; ++nt) {
      bf16x8 b = *(const bf16x8*)&h_lds[(nt * 16 + l16) * 264 + ks * 32 + lq * 8];
      acc2[nt] = MFMA(a, b, acc2[nt]);
    }
  }
  // valid rows c=0,1 live in regs 0,1 of lanes with lq==0
  if (lane < 16) {
#pragma unroll
    for (int nt = 0; nt < 4; ++nt) {
      part_lds[((wave * 4 + nt) * 16 + lane) * 2 + 0] = acc2[nt][0];
      part_lds[((wave * 4 + nt) * 16 + lane) * 2 + 1] = acc2[nt][1];
    }
  }
  __syncthreads();
  if (tid < 128) {
    const int mloc = tid >> 1, c = tid & 1;
    const int nt = mloc >> 4, l = mloc & 15;
    float s = b2[c];
#pragma unroll
    for (int w2 = 0; w2 < 4; ++w2) s += part_lds[((w2 * 4 + nt) * 16 + l) * 2 + c];
    un[(m0 + mloc) * 2 + c] = s;
  }
}

// ---------------------------------------------------------------------------
// joint + marginals: ONE WAVE per (n,b) row. Lane l holds states l (bit6=0)
// and l+64 (bit6=1); butterfly subtrees on c = e_lo+e_hi give per-bit sums.
// Zero barriers, zero LDS.
// ---------------------------------------------------------------------------
__global__ __launch_bounds__(256) void k_joint(const float* __restrict__ un,
                                               const float* __restrict__ bsum,
                                               float* __restrict__ out_marg,
                                               float* __restrict__ out_joint) {
  const int lane = threadIdx.x & 63;
  const int w = threadIdx.x >> 6;
  const int wrow = __builtin_amdgcn_readfirstlane(blockIdx.x * 4 + w);  // n*512+b
  const int b = wrow & 511;

  const float* up = un + (long)wrow * 14;   // uniform -> s_load
  float u[14];
#pragma unroll
  for (int k = 0; k < 14; ++k) u[k] = up[k];

  const float* bp = bsum + b * 128;
  const float bs_lo = bp[lane];
  const float bs_hi = bp[64 + lane];

  float umid = 0.f;
#pragma unroll
  for (int i = 1; i < 7; ++i) umid += u[2 * i + ((lane >> (6 - i)) & 1)];
  const float j_lo = bs_lo + umid + u[0];
  const float j_hi = bs_hi + umid + u[1];

  float mm = fmaxf(j_lo, j_hi);
#pragma unroll
  for (int o = 32; o; o >>= 1) mm = fmaxf(mm, __shfl_xor(mm, o, 64));
  const float e_lo = __expf(j_lo - mm);
  const float e_hi = __expf(j_hi - mm);
  const float c = e_lo + e_hi;

  // shared butterfly subtrees on c (lane bits 0..5; entity i <-> bit 6-i)
  float a1 = c + __shfl_xor(c, 16, 64);
  float A  = a1 + __shfl_xor(a1, 32, 64);       // reduced over bits {4,5}
  float e1 = c + __shfl_xor(c, 4, 64);
  float E23 = e1 + __shfl_xor(e1, 8, 64);       // reduced over bits {2,3}
  float r1_ = A + __shfl_xor(A, 4, 64);
  float R2345 = r1_ + __shfl_xor(r1_, 8, 64);   // bits {2,3,4,5}
  float s1_ = A + __shfl_xor(A, 1, 64);
  float R0145 = s1_ + __shfl_xor(s1_, 2, 64);   // bits {0,1,4,5}
  float u1_ = E23 + __shfl_xor(E23, 1, 64);
  float R0123 = u1_ + __shfl_xor(u1_, 2, 64);   // bits {0,1,2,3}

  float v0 = R2345 + __shfl_xor(R2345, 2, 64);  // varies only with bit0
  float v1 = R2345 + __shfl_xor(R2345, 1, 64);  // bit1
  float v2 = R0145 + __shfl_xor(R0145, 8, 64);  // bit2
  float v3 = R0145 + __shfl_xor(R0145, 4, 64);  // bit3
  float v4 = R0123 + __shfl_xor(R0123, 32, 64); // bit4
  float v5 = R0123 + __shfl_xor(R0123, 16, 64); // bit5
  const float T = v0 + __shfl_xor(v0, 1, 64);

  // entity-0 one-sum: full tree on e_hi
  float th = e_hi;
#pragma unroll
  for (int o = 32; o; o >>= 1) th += __shfl_xor(th, o, 64);

  const float lT = __logf(T);
  float* oj = out_joint + (long)wrow * 128;
  oj[lane] = (j_lo - mm) - lT;
  oj[64 + lane] = (j_hi - mm) - lT;

  // broadcast per-bit one-sums (v_k at lane 1<<k is the bit-k=1 sum)
  const float S0 = __shfl(v0, 1, 64);
  const float S1 = __shfl(v1, 2, 64);
  const float S2 = __shfl(v2, 4, 64);
  const float S3 = __shfl(v3, 8, 64);
  const float S4 = __shfl(v4, 16, 64);
  const float S5 = __shfl(v5, 32, 64);
  if (lane < 7) {
    const float s1v = (lane == 0) ? th
                    : (lane == 1) ? S5
                    : (lane == 2) ? S4
                    : (lane == 3) ? S3
                    : (lane == 4) ? S2
                    : (lane == 5) ? S1 : S0;
    const float s0v = T - s1v;
    out_marg[(long)wrow * 7 + lane] = __logf(s1v) - __logf(s0v);
  }
}

// ---------------------------------------------------------------------------
extern "C" void kernel_launch(void* const* d_in, const int* in_sizes, int n_in,
                              void* d_out, int out_size, void* d_ws, size_t ws_size,
                              hipStream_t stream) {
  const float* input = (const float*)d_in[0];
  const float* ctx   = (const float*)d_in[1];
  // d_in[2]=lang_input, d_in[3]=num_markables: unused by the reference
  const float* W0 = (const float*)d_in[4];
  const float* b0 = (const float*)d_in[5];
  const float* W1 = (const float*)d_in[6];
  const float* b1 = (const float*)d_in[7];
  const float* W2 = (const float*)d_in[8];
  const float* b2 = (const float*)d_in[9];
  const float* R0 = (const float*)d_in[10];
  const float* r0 = (const float*)d_in[11];
  const float* R1 = (const float*)d_in[12];
  const float* r1 = (const float*)d_in[13];

  char* ws = (char*)d_ws;
  bf16* W0f  = (bf16*)(ws + 0);         // 262144 B
  bf16* W1f  = (bf16*)(ws + 262144);    // 131072 B
  bf16* W2f  = (bf16*)(ws + 393216);    //   8192 B
  float* un  = (float*)(ws + 401408);   // 917504 B
  float* bsm = (float*)(ws + 1318912);  // 262144 B

  float* out_marg = (float*)d_out;
  float* out_joint = out_marg + 114688;

  hipLaunchKernelGGL(k_small, dim3(610), dim3(256), 0, stream,
                     ctx, R0, r0, R1, r1, bsm, W0, W1, W2, W0f, W1f, W2f);
  hipLaunchKernelGGL(k_unary, dim3(1792), dim3(256), 0, stream,
                     input, W0f, W1f, W2f, b0, b1, b2, un);
  hipLaunchKernelGGL(k_joint, dim3(4096), dim3(256), 0, stream, un, bsm, out_marg, out_joint);
}

// Round 7
// 378.522 us; speedup vs baseline: 1.2282x; 1.0273x over previous
//
#include <hip/hip_runtime.h>

typedef __bf16 bf16;
typedef bf16 bf16x8 __attribute__((ext_vector_type(8)));
typedef bf16 bf16x4 __attribute__((ext_vector_type(4)));
typedef float f32x4 __attribute__((ext_vector_type(4)));

#define MFMA(a, b, c) __builtin_amdgcn_mfma_f32_16x16x32_bf16((a), (b), (c), 0, 0, 0)

// Problem constants
// N=32, BSZ=512, NE=7, DIN=512, DH=256 ; M = N*BSZ*NE = 114688 rows
// out: marginal [32,512,7] = 114688 floats, joint [32,512,128] = 2097152 floats

// ---------------------------------------------------------------------------
// small: merged k_bsum (blocks 0..511) + k_prep (blocks 512..609).
// ---------------------------------------------------------------------------
__global__ __launch_bounds__(256) void k_small(const float* __restrict__ ctx,
                                               const float* __restrict__ R0,
                                               const float* __restrict__ r0,
                                               const float* __restrict__ R1,
                                               const float* __restrict__ r1,
                                               float* __restrict__ bsum,
                                               const float* __restrict__ W0,
                                               const float* __restrict__ W1,
                                               const float* __restrict__ W2,
                                               bf16* __restrict__ W0f,
                                               bf16* __restrict__ W1f,
                                               bf16* __restrict__ W2f) {
  const int t = threadIdx.x;
  if (blockIdx.x >= 512) {
    // ---- prep: pack W0^T, W1^T, W2^T into MFMA A-fragment order (bf16).
    // A-frag (16x16x32): lane l holds A[m=tile*16+(l&15)][k=ks*32+(l>>4)*8+j]
    int g = (blockIdx.x - 512) * 256 + t;          // 0..25087
    if (g < 16384) {                       // W0^T: 16 mtiles x 16 ksteps x 64 lanes
      int mt = g >> 10, ks = (g >> 6) & 15, lane = g & 63;
      int m = mt * 16 + (lane & 15);
      int kb = ks * 32 + (lane >> 4) * 8;
      bf16x8 v;
#pragma unroll
      for (int j = 0; j < 8; ++j) v[j] = (bf16)W0[(kb + j) * 256 + m];
      *(bf16x8*)&W0f[g * 8] = v;
    } else if (g < 24576) {                // W1^T: 16 mtiles x 8 ksteps x 64 lanes
      int h = g - 16384;
      int mt = h >> 9, ks = (h >> 6) & 7, lane = h & 63;
      int m = mt * 16 + (lane & 15);
      int kb = ks * 32 + (lane >> 4) * 8;
      bf16x8 v;
#pragma unroll
      for (int j = 0; j < 8; ++j) v[j] = (bf16)W1[(kb + j) * 256 + m];
      *(bf16x8*)&W1f[h * 8] = v;
    } else {                               // W2^T: 1 mtile (rows 0,1 valid) x 8 ksteps
      int h = g - 24576;
      int ks = h >> 6, lane = h & 63;
      int c = lane & 15;
      int kb = ks * 32 + (lane >> 4) * 8;
      bf16x8 v;
#pragma unroll
      for (int j = 0; j < 8; ++j) v[j] = (c < 2) ? (bf16)W2[(kb + j) * 2 + c] : (bf16)0.0f;
      *(bf16x8*)&W2f[h * 8] = v;
    }
    return;
  }
  // ---- bsum: relation MLP + pairwise pre-sum over the 21 pairs
  __shared__ float ctx_l[105], R0_l[320], r0_l[64], R1_l[192], r1_l[3];
  __shared__ float h2[21 * 65];
  __shared__ float bp[63];
  const int b = blockIdx.x;
  if (t < 105) ctx_l[t] = ctx[b * 105 + t];
  for (int i = t; i < 320; i += 256) R0_l[i] = R0[i];
  if (t < 64) r0_l[t] = r0[t];
  if (t < 192) R1_l[t] = R1[t];
  if (t < 3) r1_l[t] = r1[t];
  __syncthreads();
  for (int idx = t; idx < 1344; idx += 256) {
    int p = idx >> 6, u = idx & 63;
    float a = r0_l[u];
#pragma unroll
    for (int x = 0; x < 5; ++x) a += ctx_l[p * 5 + x] * R0_l[x * 64 + u];
    h2[p * 65 + u] = fmaxf(a, 0.f);
  }
  __syncthreads();
  if (t < 63) {
    int p = t / 3, y = t - p * 3;
    float a = r1_l[y];
    for (int u = 0; u < 64; ++u) a += h2[p * 65 + u] * R1_l[u * 3 + y];
    bp[t] = a;
  }
  __syncthreads();
  if (t < 128) {
    float a = 0.f;
    int pi = 0;
#pragma unroll
    for (int i = 0; i < 7; ++i)
#pragma unroll
      for (int j = i + 1; j < 7; ++j) {
        int bi = (t >> (6 - i)) & 1, bj = (t >> (6 - j)) & 1;
        a += bp[pi * 3 + bi + bj];
        ++pi;
      }
    bsum[b * 128 + t] = a;
  }
}

// ---------------------------------------------------------------------------
// unary MLP, fully fused, transposed GEMMs (best-measured config, R3):
//   D0 = W0^T(256x512) * X^T(512x64)  -> h0[m][n] in LDS (n contiguous)
//   D1 = W1^T(256x256) * h0^T         -> h1[m][n] in LDS
//   D2 = W2^T(2x256)   * h1^T         -> un[m][2] to global
// Block: 256 threads (4 waves), 64 example-rows. Wave w owns D-rows [64w,64w+64).
// Layer 0: BK=64, double-buffered reg staging, ONE barrier per K-step.
// LDS 51 KB (no bias/part buffers; partials alias dead inp_lds) -> 3 blocks/CU.
// ---------------------------------------------------------------------------
__global__ __launch_bounds__(256, 3) void k_unary(const float* __restrict__ input,
                                                  const bf16* __restrict__ W0f,
                                                  const bf16* __restrict__ W1f,
                                                  const bf16* __restrict__ W2f,
                                                  const float* __restrict__ b0,
                                                  const float* __restrict__ b1,
                                                  const float* __restrict__ b2,
                                                  float* __restrict__ un) {
  __shared__ bf16 inp_lds[2][64 * 72];   // 2 x 64 rows x 64 cols (stride 72) = 18 KB
  __shared__ bf16 h_lds[64 * 264];       // 64 rows x 256 (+8 pad) bf16 = 33 KB

  const int tid = threadIdx.x;
  const int wave = tid >> 6;
  const int lane = tid & 63;
  const int l16 = lane & 15;
  const int lq = lane >> 4;            // 0..3
  const long m0 = (long)blockIdx.x * 64;

  f32x4 acc[4][4];
#pragma unroll
  for (int i = 0; i < 4; ++i)
#pragma unroll
    for (int j = 0; j < 4; ++j) acc[i][j] = (f32x4){0.f, 0.f, 0.f, 0.f};

  // input staging map: thread -> (row r, 16-float chunk q) of the BK=64 slab
  const int r = tid >> 2;              // 0..63
  const int q = tid & 3;               // 0..3
  const float* gp = input + (m0 + r) * 512 + q * 16;
  float4 x0 = *(const float4*)(gp + 0);
  float4 x1 = *(const float4*)(gp + 4);
  float4 x2 = *(const float4*)(gp + 8);
  float4 x3 = *(const float4*)(gp + 12);

#define STAGE(BUF)                                                              \
  do {                                                                          \
    bf16x8 wlo, whi;                                                            \
    wlo[0] = (bf16)x0.x; wlo[1] = (bf16)x0.y; wlo[2] = (bf16)x0.z;              \
    wlo[3] = (bf16)x0.w; wlo[4] = (bf16)x1.x; wlo[5] = (bf16)x1.y;              \
    wlo[6] = (bf16)x1.z; wlo[7] = (bf16)x1.w;                                   \
    whi[0] = (bf16)x2.x; whi[1] = (bf16)x2.y; whi[2] = (bf16)x2.z;              \
    whi[3] = (bf16)x2.w; whi[4] = (bf16)x3.x; whi[5] = (bf16)x3.y;              \
    whi[6] = (bf16)x3.z; whi[7] = (bf16)x3.w;                                   \
    *(bf16x8*)&inp_lds[BUF][r * 72 + q * 16] = wlo;                             \
    *(bf16x8*)&inp_lds[BUF][r * 72 + q * 16 + 8] = whi;                         \
  } while (0)

  STAGE(0);
  __syncthreads();

  // ---- layer 0: K=512, 8 iters of BK=64, double-buffered ----------------
  for (int it = 0; it < 8; ++it) {
    const int cur = it & 1;
    // prefetch next slab from HBM (lands under the MFMA phase)
    if (it < 7) {
      gp += 64;
      x0 = *(const float4*)(gp + 0);
      x1 = *(const float4*)(gp + 4);
      x2 = *(const float4*)(gp + 8);
      x3 = *(const float4*)(gp + 12);
    }
    // preload all A-fragments for this iter (L2-resident)
    bf16x8 afr[2][4];
#pragma unroll
    for (int kk = 0; kk < 2; ++kk)
#pragma unroll
      for (int mt = 0; mt < 4; ++mt)
        afr[kk][mt] =
            *(const bf16x8*)&W0f[(((wave * 4 + mt) * 16 + it * 2 + kk) * 64 + lane) * 8];
#pragma unroll
    for (int kk = 0; kk < 2; ++kk) {
      bf16x8 bfr[4];
#pragma unroll
      for (int nt = 0; nt < 4; ++nt)
        bfr[nt] = *(const bf16x8*)&inp_lds[cur][(nt * 16 + l16) * 72 + kk * 32 + lq * 8];
#pragma unroll
      for (int mt = 0; mt < 4; ++mt)
#pragma unroll
        for (int nt = 0; nt < 4; ++nt) acc[mt][nt] = MFMA(afr[kk][mt], bfr[nt], acc[mt][nt]);
    }
    // stage next slab into the other buffer (prev readers of it finished
    // before the barrier that opened this iter)
    if (it < 7) STAGE(cur ^ 1);
    __syncthreads();
  }
#undef STAGE

  // epilogue 0: h0 = relu(D0 + b0) -> h_lds[m][n]
#pragma unroll
  for (int mt = 0; mt < 4; ++mt) {
    const int nbase = (wave * 4 + mt) * 16 + lq * 4;
    const float4 bb = *(const float4*)&b0[nbase];
#pragma unroll
    for (int nt = 0; nt < 4; ++nt) {
      const int m = nt * 16 + l16;
      bf16x4 hv;
      hv[0] = (bf16)fmaxf(acc[mt][nt][0] + bb.x, 0.f);
      hv[1] = (bf16)fmaxf(acc[mt][nt][1] + bb.y, 0.f);
      hv[2] = (bf16)fmaxf(acc[mt][nt][2] + bb.z, 0.f);
      hv[3] = (bf16)fmaxf(acc[mt][nt][3] + bb.w, 0.f);
      *(bf16x4*)&h_lds[m * 264 + nbase] = hv;
    }
  }
  __syncthreads();

  // ---- layer 1: K=256, 8 ksteps ----------------------------------------
#pragma unroll
  for (int i = 0; i < 4; ++i)
#pragma unroll
    for (int j = 0; j < 4; ++j) acc[i][j] = (f32x4){0.f, 0.f, 0.f, 0.f};
  for (int ks = 0; ks < 8; ++ks) {
    bf16x8 bfr[4];
#pragma unroll
    for (int nt = 0; nt < 4; ++nt)
      bfr[nt] = *(const bf16x8*)&h_lds[(nt * 16 + l16) * 264 + ks * 32 + lq * 8];
#pragma unroll
    for (int mt = 0; mt < 4; ++mt) {
      bf16x8 a = *(const bf16x8*)&W1f[(((wave * 4 + mt) * 8 + ks) * 64 + lane) * 8];
#pragma unroll
      for (int nt = 0; nt < 4; ++nt) acc[mt][nt] = MFMA(a, bfr[nt], acc[mt][nt]);
    }
  }
  __syncthreads();   // everyone done reading h0 before overwrite

  // epilogue 1: h1 = relu(D1 + b1) -> h_lds[m][n]
#pragma unroll
  for (int mt = 0; mt < 4; ++mt) {
    const int nbase = (wave * 4 + mt) * 16 + lq * 4;
    const float4 bb = *(const float4*)&b1[nbase];
#pragma unroll
    for (int nt = 0; nt < 4; ++nt) {
      const int m = nt * 16 + l16;
      bf16x4 hv;
      hv[0] = (bf16)fmaxf(acc[mt][nt][0] + bb.x, 0.f);
      hv[1] = (bf16)fmaxf(acc[mt][nt][1] + bb.y, 0.f);
      hv[2] = (bf16)fmaxf(acc[mt][nt][2] + bb.z, 0.f);
      hv[3] = (bf16)fmaxf(acc[mt][nt][3] + bb.w, 0.f);
      *(bf16x4*)&h_lds[m * 264 + nbase] = hv;
    }
  }
  __syncthreads();

  // ---- layer 2: K=256 split across waves (2 ksteps each) ----------------
  float* part = (float*)&inp_lds[0][0];   // inp_lds is dead; reuse for partials
  f32x4 acc2[4];
#pragma unroll
  for (int i = 0; i < 4; ++i) acc2[i] = (f32x4){0.f, 0.f, 0.f, 0.f};
#pragma unroll
  for (int s = 0; s < 2; ++s) {
    const int ks = wave * 2 + s;
    bf16x8 a = *(const bf16x8*)&W2f[(ks * 64 + lane) * 8];
#pragma unroll
    for (int nt = 0; nt < 4; ++nt) {
      bf16x8 b = *(const bf16x8*)&h_lds[(nt * 16 + l16) * 264 + ks * 32 + lq * 8];
      acc2[nt] = MFMA(a, b, acc2[nt]);
    }
  }
  // valid rows c=0,1 live in regs 0,1 of lanes with lq==0
  if (lane < 16) {
#pragma unroll
    for (int nt = 0; nt < 4; ++nt) {
      part[((wave * 4 + nt) * 16 + lane) * 2 + 0] = acc2[nt][0];
      part[((wave * 4 + nt) * 16 + lane) * 2 + 1] = acc2[nt][1];
    }
  }
  __syncthreads();
  if (tid < 128) {
    const int mloc = tid >> 1, c = tid & 1;
    const int nt = mloc >> 4, l = mloc & 15;
    float s = b2[c];
#pragma unroll
    for (int w2 = 0; w2 < 4; ++w2) s += part[((w2 * 4 + nt) * 16 + l) * 2 + c];
    un[(m0 + mloc) * 2 + c] = s;
  }
}

// ---------------------------------------------------------------------------
// joint + marginals: ONE WAVE per (n,b) row. Lane l holds states l (bit6=0)
// and l+64 (bit6=1); butterfly subtrees on c = e_lo+e_hi give per-bit sums.
// Zero barriers, zero LDS.
// ---------------------------------------------------------------------------
__global__ __launch_bounds__(256) void k_joint(const float* __restrict__ un,
                                               const float* __restrict__ bsum,
                                               float* __restrict__ out_marg,
                                               float* __restrict__ out_joint) {
  const int lane = threadIdx.x & 63;
  const int w = threadIdx.x >> 6;
  const int wrow = __builtin_amdgcn_readfirstlane(blockIdx.x * 4 + w);  // n*512+b
  const int b = wrow & 511;

  const float* up = un + (long)wrow * 14;   // uniform -> s_load
  float u[14];
#pragma unroll
  for (int k = 0; k < 14; ++k) u[k] = up[k];

  const float* bp = bsum + b * 128;
  const float bs_lo = bp[lane];
  const float bs_hi = bp[64 + lane];

  float umid = 0.f;
#pragma unroll
  for (int i = 1; i < 7; ++i) umid += u[2 * i + ((lane >> (6 - i)) & 1)];
  const float j_lo = bs_lo + umid + u[0];
  const float j_hi = bs_hi + umid + u[1];

  float mm = fmaxf(j_lo, j_hi);
#pragma unroll
  for (int o = 32; o; o >>= 1) mm = fmaxf(mm, __shfl_xor(mm, o, 64));
  const float e_lo = __expf(j_lo - mm);
  const float e_hi = __expf(j_hi - mm);
  const float c = e_lo + e_hi;

  // shared butterfly subtrees on c (lane bits 0..5; entity i <-> bit 6-i)
  float a1 = c + __shfl_xor(c, 16, 64);
  float A  = a1 + __shfl_xor(a1, 32, 64);       // reduced over bits {4,5}
  float e1 = c + __shfl_xor(c, 4, 64);
  float E23 = e1 + __shfl_xor(e1, 8, 64);       // reduced over bits {2,3}
  float r1_ = A + __shfl_xor(A, 4, 64);
  float R2345 = r1_ + __shfl_xor(r1_, 8, 64);   // bits {2,3,4,5}
  float s1_ = A + __shfl_xor(A, 1, 64);
  float R0145 = s1_ + __shfl_xor(s1_, 2, 64);   // bits {0,1,4,5}
  float u1_ = E23 + __shfl_xor(E23, 1, 64);
  float R0123 = u1_ + __shfl_xor(u1_, 2, 64);   // bits {0,1,2,3}

  float v0 = R2345 + __shfl_xor(R2345, 2, 64);  // varies only with bit0
  float v1 = R2345 + __shfl_xor(R2345, 1, 64);  // bit1
  float v2 = R0145 + __shfl_xor(R0145, 8, 64);  // bit2
  float v3 = R0145 + __shfl_xor(R0145, 4, 64);  // bit3
  float v4 = R0123 + __shfl_xor(R0123, 32, 64); // bit4
  float v5 = R0123 + __shfl_xor(R0123, 16, 64); // bit5
  const float T = v0 + __shfl_xor(v0, 1, 64);

  // entity-0 one-sum: full tree on e_hi
  float th = e_hi;
#pragma unroll
  for (int o = 32; o; o >>= 1) th += __shfl_xor(th, o, 64);

  const float lT = __logf(T);
  float* oj = out_joint + (long)wrow * 128;
  oj[lane] = (j_lo - mm) - lT;
  oj[64 + lane] = (j_hi - mm) - lT;

  // broadcast per-bit one-sums (v_k at lane 1<<k is the bit-k=1 sum)
  const float S0 = __shfl(v0, 1, 64);
  const float S1 = __shfl(v1, 2, 64);
  const float S2 = __shfl(v2, 4, 64);
  const float S3 = __shfl(v3, 8, 64);
  const float S4 = __shfl(v4, 16, 64);
  const float S5 = __shfl(v5, 32, 64);
  if (lane < 7) {
    const float s1v = (lane == 0) ? th
                    : (lane == 1) ? S5
                    : (lane == 2) ? S4
                    : (lane == 3) ? S3
                    : (lane == 4) ? S2
                    : (lane == 5) ? S1 : S0;
    const float s0v = T - s1v;
    out_marg[(long)wrow * 7 + lane] = __logf(s1v) - __logf(s0v);
  }
}

// ---------------------------------------------------------------------------
extern "C" void kernel_launch(void* const* d_in, const int* in_sizes, int n_in,
                              void* d_out, int out_size, void* d_ws, size_t ws_size,
                              hipStream_t stream) {
  const float* input = (const float*)d_in[0];
  const float* ctx   = (const float*)d_in[1];
  // d_in[2]=lang_input, d_in[3]=num_markables: unused by the reference
  const float* W0 = (const float*)d_in[4];
  const float* b0 = (const float*)d_in[5];
  const float* W1 = (const float*)d_in[6];
  const float* b1 = (const float*)d_in[7];
  const float* W2 = (const float*)d_in[8];
  const float* b2 = (const float*)d_in[9];
  const float* R0 = (const float*)d_in[10];
  const float* r0 = (const float*)d_in[11];
  const float* R1 = (const float*)d_in[12];
  const float* r1 = (const float*)d_in[13];

  char* ws = (char*)d_ws;
  bf16* W0f  = (bf16*)(ws + 0);         // 262144 B
  bf16* W1f  = (bf16*)(ws + 262144);    // 131072 B
  bf16* W2f  = (bf16*)(ws + 393216);    //   8192 B
  float* un  = (float*)(ws + 401408);   // 917504 B
  float* bsm = (float*)(ws + 1318912);  // 262144 B

  float* out_marg = (float*)d_out;
  float* out_joint = out_marg + 114688;

  hipLaunchKernelGGL(k_small, dim3(610), dim3(256), 0, stream,
                     ctx, R0, r0, R1, r1, bsm, W0, W1, W2, W0f, W1f, W2f);
  hipLaunchKernelGGL(k_unary, dim3(1792), dim3(256), 0, stream,
                     input, W0f, W1f, W2f, b0, b1, b2, un);
  hipLaunchKernelGGL(k_joint, dim3(4096), dim3(256), 0, stream, un, bsm, out_marg, out_joint);
}